// Round 2
// baseline (77.034 us; speedup 1.0000x reference)
//
#include <hip/hip_runtime.h>
#include <math.h>

// Problem constants (match reference)
#define BB   256
#define KK   16
#define NBIN 128
#define GG   (NBIN * NBIN)     // 16384 bins per batch
#define NT   1024              // threads per block
#define SPT  (GG / NT)         // 16 bins per thread

// Guaranteed single-instruction exp2. Our argument is always <= 0 (quadratic
// form of a PD/diagonal-positive inverse, scaled by -0.5*log2e), so v_exp_f32's
// flush-to-zero underflow for very negative inputs is exactly the reference
// semantics (exp(-huge) -> 0). No denormal fixup wanted.
__device__ __forceinline__ float raw_exp2(float x) {
#if __has_builtin(__builtin_amdgcn_exp2f)
    return __builtin_amdgcn_exp2f(x);
#else
    float r;
    // s_nop covers the VALU-trans write -> VALU read hazard conservatively,
    // since the hazard recognizer may not see through inline asm.
    asm volatile("v_exp_f32 %0, %1\n\ts_nop 1" : "=v"(r) : "v"(x));
    return r;
#endif
}

// One block per batch. Thread t owns bins g = s*1024 + t (s=0..15):
//   j = g & 127  (constant per thread)  -> dv fixed per (thread,k)
//   i = 8*s + (t>>7)                    -> du varies over s
// Coalesced stores: for fixed s, consecutive tids hit consecutive addresses.
__global__ __launch_bounds__(NT) void gmm_hist_kernel(
    const float* __restrict__ mu,     // [B,K,2]
    const float* __restrict__ sigma,  // [B,K,2]
    const float* __restrict__ cov12,  // [B,K]
    const float* __restrict__ pi_,    // [B,K]
    float* __restrict__ out)          // [B,128,128]
{
    const int b   = blockIdx.x;
    const int tid = threadIdx.x;

    // Per-mixture params packed for ds_read_b128:
    //   s_par[2k+0] = {mu_u, mu_v, ia*cs, 2*ib*cs}
    //   s_par[2k+1] = {ic*cs, coef, 0, 0}
    __shared__ float4 s_par[2 * KK];
    __shared__ float  s_wsum[NT / 64];
    __shared__ float  s_total;

    // ---- per-mixture precompute (threads 0..15), mirrors reference exactly ----
    if (tid < KK) {
        const int idx = b * KK + tid;
        const float m_u = mu[idx * 2 + 0];
        const float m_v = mu[idx * 2 + 1];
        const float su  = fmaxf(sigma[idx * 2 + 0], 0.001f);
        const float sv  = fmaxf(sigma[idx * 2 + 1], 0.001f);
        const float su2 = su * su;
        const float sv2 = sv * sv;
        const float c11 = su2 + 1e-6f;
        const float c22 = sv2 + 1e-6f;
        const float off = cov12[idx];
        const float det_full = c11 * c22 - off * off;
        const bool  valid    = (det_full > 0.0f);   // NaN compares false -> fallback, like ref
        const float det_safe = valid ? det_full : 1.0f;
        const float ia  = valid ? (c22 / det_safe) : (1.0f / su2);
        const float ib  = valid ? (-off / det_safe) : 0.0f;
        const float ic  = valid ? (c11 / det_safe) : (1.0f / sv2);
        const float det = valid ? det_full : (su2 * sv2);
        const float coef = pi_[idx] / (6.283185307179586f * sqrtf(det + 1e-6f));
        const float cs = -0.7213475204444817f;      // -0.5 * log2(e), folded into exponent
        s_par[2 * tid + 0] = make_float4(m_u, m_v, ia * cs, (2.0f * ib) * cs);
        s_par[2 * tid + 1] = make_float4(ic * cs, coef, 0.0f, 0.0f);
    }
    __syncthreads();

    const float step = 4.0f / 127.0f;               // linspace(-2,2,128) step
    const int   j    = tid & (NBIN - 1);
    const int   i0   = tid >> 7;                    // 0..7
    const float gv   = -2.0f + (float)j * step;

    // Row coordinates for this thread's 16 bins (exact per-bin formula, no drift)
    float u_s[SPT];
    #pragma unroll
    for (int s = 0; s < SPT; ++s)
        u_s[s] = -2.0f + (float)(i0 + 8 * s) * step;

    float acc[SPT];
    #pragma unroll
    for (int s = 0; s < SPT; ++s) acc[s] = 0.0f;

    // ---- main accumulation: 16 mixtures x 16 bins per thread ----
    // Inner body: v_sub + v_fma + v_fma + v_exp + v_fma. Direct quadratic-form
    // evaluation (NOT an expanded polynomial in s) — expanded forms cancel
    // catastrophically for narrow Gaussians (ia up to 1e6).
    #pragma unroll
    for (int k = 0; k < KK; ++k) {
        const float4 p0 = s_par[2 * k + 0];         // ds_read_b128
        const float4 p1 = s_par[2 * k + 1];         // ds_read_b128
        const float muu  = p0.x;
        const float dv   = gv - p0.y;
        const float ia   = p0.z;                    // pre-scaled by -0.5*log2e
        const float Bp   = p0.w * dv;
        const float Ap   = p1.x * (dv * dv);
        const float coef = p1.y;
        #pragma unroll
        for (int s = 0; s < SPT; ++s) {
            const float du = u_s[s] - muu;                  // v_sub
            const float t  = __builtin_fmaf(ia, du, Bp);    // v_fma
            const float m  = __builtin_fmaf(du, t, Ap);     // v_fma  (m <= 0 always)
            const float e  = raw_exp2(m);                   // v_exp_f32
            acc[s] = __builtin_fmaf(coef, e, acc[s]);       // v_fma
        }
    }

    // ---- block-wide sum for per-batch normalization ----
    float local = 0.0f;
    #pragma unroll
    for (int s = 0; s < SPT; ++s) local += acc[s];

    #pragma unroll
    for (int off = 32; off >= 1; off >>= 1)
        local += __shfl_down(local, off, 64);

    const int wave = tid >> 6;
    const int lane = tid & 63;
    if (lane == 0) s_wsum[wave] = local;
    __syncthreads();

    if (tid == 0) {
        float t = 0.0f;
        #pragma unroll
        for (int w = 0; w < NT / 64; ++w) t += s_wsum[w];
        s_total = (t > 0.0f) ? t : 1.0f;                    // ref: where(s>0, s, 1)
    }
    __syncthreads();

    const float inv = 1.0f / s_total;
    float* outb = out + (size_t)b * GG;
    #pragma unroll
    for (int s = 0; s < SPT; ++s)
        outb[s * NT + tid] = acc[s] * inv;                  // coalesced dword stores
}

extern "C" void kernel_launch(void* const* d_in, const int* in_sizes, int n_in,
                              void* d_out, int out_size, void* d_ws, size_t ws_size,
                              hipStream_t stream) {
    const float* mu    = (const float*)d_in[0];
    const float* sigma = (const float*)d_in[1];
    const float* cov12 = (const float*)d_in[2];
    const float* pi_   = (const float*)d_in[3];
    float* out = (float*)d_out;

    hipLaunchKernelGGL(gmm_hist_kernel, dim3(BB), dim3(NT), 0, stream,
                       mu, sigma, cov12, pi_, out);
}

// Round 3
// 76.464 us; speedup vs baseline: 1.0074x; 1.0074x over previous
//
#include <hip/hip_runtime.h>
#include <math.h>

// Problem constants (match reference)
#define BB   256
#define KK   16
#define NBIN 128
#define GG   (NBIN * NBIN)     // 16384 bins per batch
#define NT   1024              // threads per block
#define SPT  (GG / NT)         // 16 bins per thread

// Guaranteed single-instruction exp2. Our argument is always <= 0, so
// v_exp_f32's flush-to-zero underflow for very negative inputs matches the
// reference semantics (exp(-huge) -> 0).
__device__ __forceinline__ float raw_exp2(float x) {
#if __has_builtin(__builtin_amdgcn_exp2f)
    return __builtin_amdgcn_exp2f(x);
#else
    float r;
    asm volatile("v_exp_f32 %0, %1\n\ts_nop 1" : "=v"(r) : "v"(x));
    return r;
#endif
}

// One block per batch (normalization needs the whole batch in one workgroup).
// Thread t owns bins g = s*1024 + t (s=0..15):
//   j = g & 127  (constant per thread)  -> dv fixed per (thread,k)
//   i = 8*s + (t>>7)                    -> du = base_k + 8*s*step
// Coalesced stores: for fixed s, consecutive tids hit consecutive addresses.
//
// Register budget note: 1024-thread workgroup = 16 waves = 4 waves/SIMD
// => hard cap 128 VGPRs/wave. We keep live state ~60: acc[16] (required
// until the normalization sum is known), 8-wide chain temps, 6 params.
// No u_s[] array: du is formed by adding a compile-time constant to a
// per-k base, which is the same instruction count as the old subtract.
__global__ __launch_bounds__(NT) void gmm_hist_kernel(
    const float* __restrict__ mu,     // [B,K,2]
    const float* __restrict__ sigma,  // [B,K,2]
    const float* __restrict__ cov12,  // [B,K]
    const float* __restrict__ pi_,    // [B,K]
    float* __restrict__ out)          // [B,128,128]
{
    const int b   = blockIdx.x;
    const int tid = threadIdx.x;

    // Per-mixture params packed for ds_read_b128:
    //   s_par[2k+0] = {mu_u, mu_v, ia*cs, 2*ib*cs}
    //   s_par[2k+1] = {ic*cs, coef, 0, 0}
    __shared__ float4 s_par[2 * KK];
    __shared__ float  s_wsum[NT / 64];
    __shared__ float  s_total;

    // ---- per-mixture precompute (threads 0..15), mirrors reference exactly ----
    if (tid < KK) {
        const int idx = b * KK + tid;
        const float m_u = mu[idx * 2 + 0];
        const float m_v = mu[idx * 2 + 1];
        const float su  = fmaxf(sigma[idx * 2 + 0], 0.001f);
        const float sv  = fmaxf(sigma[idx * 2 + 1], 0.001f);
        const float su2 = su * su;
        const float sv2 = sv * sv;
        const float c11 = su2 + 1e-6f;
        const float c22 = sv2 + 1e-6f;
        const float off = cov12[idx];
        const float det_full = c11 * c22 - off * off;
        const bool  valid    = (det_full > 0.0f);   // NaN compares false -> fallback, like ref
        const float det_safe = valid ? det_full : 1.0f;
        const float ia  = valid ? (c22 / det_safe) : (1.0f / su2);
        const float ib  = valid ? (-off / det_safe) : 0.0f;
        const float ic  = valid ? (c11 / det_safe) : (1.0f / sv2);
        const float det = valid ? det_full : (su2 * sv2);
        const float coef = pi_[idx] / (6.283185307179586f * sqrtf(det + 1e-6f));
        const float cs = -0.7213475204444817f;      // -0.5 * log2(e), folded into exponent
        s_par[2 * tid + 0] = make_float4(m_u, m_v, ia * cs, (2.0f * ib) * cs);
        s_par[2 * tid + 1] = make_float4(ic * cs, coef, 0.0f, 0.0f);
    }
    __syncthreads();

    const float step = 4.0f / 127.0f;               // linspace(-2,2,128) step
    const int   j    = tid & (NBIN - 1);
    const int   i0   = tid >> 7;                    // 0..7
    const float gv   = -2.0f + (float)j * step;
    const float u0   = -2.0f + (float)i0 * step;    // row coord at s=0

    float acc[SPT];
    #pragma unroll
    for (int s = 0; s < SPT; ++s) acc[s] = 0.0f;

    // ---- main accumulation: 16 mixtures x 16 bins per thread ----
    // Body per eval: v_add(du) + v_fma + v_fma + v_exp + v_fma.
    // Direct quadratic-form evaluation (NOT expanded in s): expanded forms
    // cancel catastrophically for narrow Gaussians (ia up to ~1e6).
    #pragma unroll
    for (int k = 0; k < KK; ++k) {
        const float4 p0 = s_par[2 * k + 0];         // ds_read_b128
        const float4 p1 = s_par[2 * k + 1];         // ds_read_b128
        const float dv   = gv - p0.y;
        const float ia   = p0.z;                    // pre-scaled by -0.5*log2e
        const float Bp   = p0.w * dv;
        const float Ap   = p1.x * (dv * dv);
        const float coef = p1.y;
        const float base = u0 - p0.x;               // du at s=0

        // Two groups of 8: phase-separated (m -> exp -> acc) so the trans
        // pipe gets batched work and chain temps stay at 8 wide.
        #pragma unroll
        for (int h = 0; h < SPT; h += 8) {
            float m8[8];
            #pragma unroll
            for (int t = 0; t < 8; ++t) {
                const float du = base + (float)(8 * (h + t)) * step;  // v_add (lit)
                const float tt = __builtin_fmaf(ia, du, Bp);          // v_fma
                m8[t] = __builtin_fmaf(du, tt, Ap);                   // v_fma (<= 0)
            }
            float e8[8];
            #pragma unroll
            for (int t = 0; t < 8; ++t) e8[t] = raw_exp2(m8[t]);      // v_exp_f32
            #pragma unroll
            for (int t = 0; t < 8; ++t)
                acc[h + t] = __builtin_fmaf(coef, e8[t], acc[h + t]); // v_fma
        }
    }

    // ---- block-wide sum for per-batch normalization ----
    float local = 0.0f;
    #pragma unroll
    for (int s = 0; s < SPT; ++s) local += acc[s];

    #pragma unroll
    for (int off = 32; off >= 1; off >>= 1)
        local += __shfl_down(local, off, 64);

    const int wave = tid >> 6;
    const int lane = tid & 63;
    if (lane == 0) s_wsum[wave] = local;
    __syncthreads();

    if (tid == 0) {
        float t = 0.0f;
        #pragma unroll
        for (int w = 0; w < NT / 64; ++w) t += s_wsum[w];
        s_total = (t > 0.0f) ? t : 1.0f;                    // ref: where(s>0, s, 1)
    }
    __syncthreads();

    const float inv = 1.0f / s_total;
    float* outb = out + (size_t)b * GG;
    #pragma unroll
    for (int s = 0; s < SPT; ++s)
        outb[s * NT + tid] = acc[s] * inv;                  // coalesced dword stores
}

extern "C" void kernel_launch(void* const* d_in, const int* in_sizes, int n_in,
                              void* d_out, int out_size, void* d_ws, size_t ws_size,
                              hipStream_t stream) {
    const float* mu    = (const float*)d_in[0];
    const float* sigma = (const float*)d_in[1];
    const float* cov12 = (const float*)d_in[2];
    const float* pi_   = (const float*)d_in[3];
    float* out = (float*)d_out;

    hipLaunchKernelGGL(gmm_hist_kernel, dim3(BB), dim3(NT), 0, stream,
                       mu, sigma, cov12, pi_, out);
}